// Round 4
// baseline (27.383 us; speedup 1.0000x reference)
//
#include <hip/hip_runtime.h>

#define TT 4096
#define DD 256
#define BT 64
#define HW 64
#define WIN 192

typedef __attribute__((ext_vector_type(8))) short short8;
typedef __attribute__((ext_vector_type(4))) float f32x4;
typedef __attribute__((ext_vector_type(4))) unsigned int u32x4;

__device__ __forceinline__ unsigned int f2bf(float f) {
    unsigned int u = __builtin_bit_cast(unsigned int, f);
    u += 0x7fffu + ((u >> 16) & 1u);
    return u >> 16;                      // low 16 bits = bf16 (RNE)
}
__device__ __forceinline__ float bf2f(unsigned int h) {
    unsigned int u = h << 16;
    return __builtin_bit_cast(float, u);
}
// byte offset of 16B quarter q in a 64B row, XOR-swizzled (conflict-free both sides)
__device__ __forceinline__ int qswz(int row, int q) {
    return row * 64 + ((q ^ ((row >> 1) & 3)) << 4);
}

__global__ __launch_bounds__(512, 2)
void distattn_kernel(const float* __restrict__ x,
                     const float* __restrict__ mask,
                     const float* __restrict__ Win,
                     const float* __restrict__ bin,
                     float* __restrict__ out)
{
    __shared__ __align__(16) unsigned short xT[2][256][32]; // v^T hi/lo-interleaved, swizzled (32KB)
    __shared__ __align__(16) unsigned short yB[64][256];    // y bf16, chunk-swizzled by (i&7) (32KB)
    __shared__ __align__(16) unsigned short Wl[2][256][32]; // W chunks bf16, swizzled (32KB)
    __shared__ float wv[WIN];
    __shared__ float rp[WIN];
    __shared__ unsigned short rpb[WIN];
    __shared__ float sp[8][BT];
    __shared__ float s_l[BT];

    const int tid  = threadIdx.x;
    const int orig = blockIdx.x;
    const int wg   = (orig & 7) * 32 + (orig >> 3);   // XCD-contiguous row tiles
    const int b    = wg >> 6;
    const int r0   = (wg & 63) * BT;
    const int base = r0 - HW;

    const int w  = tid >> 6, lane = tid & 63;
    const int lr = lane & 15, lg = lane >> 4;
    const int wr = w >> 2,   wc = w & 3;

    const float INV_E = 0.36787944117144233f;

    // ---- tables ----
    if (tid < WIN) {
        float rv = __expf(-(float)tid * INV_E);
        rp[tid]  = rv;
        rpb[tid] = (unsigned short)f2bf(rv);
        int j = base + tid;
        wv[tid] = (j >= 0 && j < TT) ? __expf(mask[b * TT + j] * INV_E) : 0.0f;
    }

    // ---- phase-1 staging helpers (thread: column c, k-half) ----
    const int c    = tid >> 1;
    const int half = tid & 1;
    const float* xcol = x + (size_t)b * TT * DD + c;

    auto xload = [&](int ch, float* xv) {
        int t0 = ch * 16 + half * 8;
        #pragma unroll
        for (int s = 0; s < 8; ++s) {
            int j = base + t0 + s;
            j = min(max(j, 0), TT - 1);
            xv[s] = xcol[(size_t)j * DD];
        }
    };
    auto xstore = [&](int ch, const float* xv, int buf) {
        int t0 = ch * 16 + half * 8;
        unsigned int pk[8];
        #pragma unroll
        for (int s = 0; s < 8; ++s) {
            float v = xv[s] * wv[t0 + s];
            unsigned int hi = f2bf(v);
            float lo = v - bf2f(hi);
            pk[s] = (hi & 0xffffu) | (f2bf(lo) << 16);   // u even=hi, odd=lo
        }
        char* bp = (char*)(&xT[buf][0][0]);
        *(u32x4*)(bp + qswz(c, 2 * half))     = (u32x4){pk[0], pk[1], pk[2], pk[3]};
        *(u32x4*)(bp + qswz(c, 2 * half + 1)) = (u32x4){pk[4], pk[5], pk[6], pk[7]};
    };

    f32x4 acc1[2][4];
    #pragma unroll
    for (int m = 0; m < 2; ++m)
        #pragma unroll
        for (int n = 0; n < 4; ++n) acc1[m][n] = (f32x4){0.f, 0.f, 0.f, 0.f};

    auto p1mm = [&](int ch, int buf) {
        short8 afr[2], bfr[4];
        #pragma unroll
        for (int m = 0; m < 2; ++m) {
            int i = 32 * wr + 16 * m + lr;
            unsigned short a[4];
            #pragma unroll
            for (int jj = 0; jj < 4; ++jj) {
                int d = i + HW - (ch * 16 + 4 * lg + jj);
                d = d < 0 ? -d : d;
                a[jj] = rpb[d];
            }
            afr[m] = (short8){(short)a[0], (short)a[0], (short)a[1], (short)a[1],
                              (short)a[2], (short)a[2], (short)a[3], (short)a[3]};
        }
        const char* bp = (const char*)(&xT[buf][0][0]);
        #pragma unroll
        for (int n = 0; n < 4; ++n)
            bfr[n] = *(const short8*)(bp + qswz(64 * wc + 16 * n + lr, lg));
        #pragma unroll
        for (int m = 0; m < 2; ++m)
            #pragma unroll
            for (int n = 0; n < 4; ++n)
                acc1[m][n] = __builtin_amdgcn_mfma_f32_16x16x32_bf16(afr[m], bfr[n], acc1[m][n], 0, 0, 0);
    };

    float rA[8], rB[8];
    xload(0, rA);
    __syncthreads();                      // tables ready

    // attn row sums (bias term) while chunk-0 loads fly
    {
        int row = tid & 63, q = tid >> 6;
        float s = 0.0f;
        #pragma unroll
        for (int tt = 0; tt < 24; ++tt) {
            int t = 24 * q + tt;
            int d = row + HW - t; d = (d < 0) ? -d : d;
            s = fmaf(rp[d], wv[t], s);
        }
        sp[q][row] = s;
    }

    xstore(0, rA, 0);
    xload(1, rA);
    __syncthreads();                      // xT[0] ready

    // ---- phase 1: 12 chunks, 2-ahead loads, convert-late ----
    #pragma unroll 1
    for (int ch = 0; ch < 12; ch += 2) {
        if (ch + 2 < 12) xload(ch + 2, rB);
        p1mm(ch, 0);
        xstore(ch + 1, rA, 1);
        __syncthreads();

        if (ch + 3 < 12) xload(ch + 3, rA);
        p1mm(ch + 1, 1);
        if (ch + 2 < 12) xstore(ch + 2, rB, 0);
        __syncthreads();
    }

    // ---- W staging helpers ----
    auto wload = [&](int ch, float4* w4) {
        #pragma unroll
        for (int it = 0; it < 2; ++it) {
            int U = tid + (it << 9);
            int row = U >> 2, qu = U & 3;
            const float* gp = Win + row * DD + 32 * ch + 8 * qu;
            w4[2 * it]     = *(const float4*)(gp);
            w4[2 * it + 1] = *(const float4*)(gp + 4);
        }
    };
    auto wstore = [&](const float4* w4, int buf) {
        char* bp = (char*)(&Wl[buf][0][0]);
        #pragma unroll
        for (int it = 0; it < 2; ++it) {
            int U = tid + (it << 9);
            int row = U >> 2, qu = U & 3;
            unsigned int p0 = (f2bf(w4[2*it].x)   & 0xffffu) | (f2bf(w4[2*it].y)   << 16);
            unsigned int p1 = (f2bf(w4[2*it].z)   & 0xffffu) | (f2bf(w4[2*it].w)   << 16);
            unsigned int p2 = (f2bf(w4[2*it+1].x) & 0xffffu) | (f2bf(w4[2*it+1].y) << 16);
            unsigned int p3 = (f2bf(w4[2*it+1].z) & 0xffffu) | (f2bf(w4[2*it+1].w) << 16);
            *(u32x4*)(bp + qswz(row, qu)) = (u32x4){p0, p1, p2, p3};
        }
    };

    float4 wA[4], wB[4];
    wload(0, wA);

    // ---- y epilogue: acc1 -> yB (bf16, chunk-swizzled) ----
    {
        char* yp = (char*)(&yB[0][0]);
        #pragma unroll
        for (int m = 0; m < 2; ++m)
            #pragma unroll
            for (int j = 0; j < 4; ++j) {
                int i = 32 * wr + 16 * m + 4 * lg + j;
                #pragma unroll
                for (int n = 0; n < 4; ++n) {
                    int col = 64 * wc + 16 * n + lr;
                    *(unsigned short*)(yp + i * 512 + (((col >> 3) ^ (i & 7)) << 4) + (col & 7) * 2)
                        = (unsigned short)f2bf(acc1[m][n][j]);
                }
            }
    }
    if (tid < BT) {
        float s = 0.0f;
        #pragma unroll
        for (int q = 0; q < 8; ++q) s += sp[q][tid];
        s_l[tid] = s;
    }
    wstore(wA, 0);
    wload(1, wA);
    __syncthreads();                      // yB + Wl[0] + s_l ready

    // ---- phase 2: out = y @ W^T, 8 chunks, 2-ahead ----
    f32x4 acc2[2][4];
    #pragma unroll
    for (int m = 0; m < 2; ++m)
        #pragma unroll
        for (int n = 0; n < 4; ++n) acc2[m][n] = (f32x4){0.f, 0.f, 0.f, 0.f};

    auto p2mm = [&](int kk, int buf) {
        short8 afr[2], bfr[4];
        const char* yp = (const char*)(&yB[0][0]);
        #pragma unroll
        for (int m = 0; m < 2; ++m) {
            int i = 32 * wr + 16 * m + lr;
            afr[m] = *(const short8*)(yp + i * 512 + (((4 * kk + lg) ^ (i & 7)) << 4));
        }
        const char* bp = (const char*)(&Wl[buf][0][0]);
        #pragma unroll
        for (int n = 0; n < 4; ++n)
            bfr[n] = *(const short8*)(bp + qswz(64 * wc + 16 * n + lr, lg));
        #pragma unroll
        for (int m = 0; m < 2; ++m)
            #pragma unroll
            for (int n = 0; n < 4; ++n)
                acc2[m][n] = __builtin_amdgcn_mfma_f32_16x16x32_bf16(afr[m], bfr[n], acc2[m][n], 0, 0, 0);
    };

    #pragma unroll 1
    for (int kk = 0; kk < 8; kk += 2) {
        if (kk + 2 < 8) wload(kk + 2, wB);
        p2mm(kk, 0);
        wstore(wA, 1);
        __syncthreads();

        if (kk + 3 < 8) wload(kk + 3, wA);
        p2mm(kk + 1, 1);
        if (kk + 2 < 8) wstore(wB, 0);
        __syncthreads();
    }

    // ---- out epilogue (validated C/D map: row=(lane>>4)*4+j, col=lane&15) ----
    float bcol[4];
    #pragma unroll
    for (int n = 0; n < 4; ++n) bcol[n] = bin[64 * wc + 16 * n + lr];
    float* ob = out + ((size_t)b * TT + r0) * DD;
    #pragma unroll
    for (int m = 0; m < 2; ++m)
        #pragma unroll
        for (int j = 0; j < 4; ++j) {
            int i = 32 * wr + 16 * m + 4 * lg + j;
            float si = s_l[i];
            #pragma unroll
            for (int n = 0; n < 4; ++n)
                ob[(size_t)i * DD + 64 * wc + 16 * n + lr] = acc2[m][n][j] + si * bcol[n];
        }
}

extern "C" void kernel_launch(void* const* d_in, const int* in_sizes, int n_in,
                              void* d_out, int out_size, void* d_ws, size_t ws_size,
                              hipStream_t stream) {
    const float* x    = (const float*)d_in[0];
    const float* mask = (const float*)d_in[1];
    const float* Win  = (const float*)d_in[2];
    const float* bin  = (const float*)d_in[3];
    float* out = (float*)d_out;

    const int nb = in_sizes[0] / (TT * DD);   // batches (4)
    hipLaunchKernelGGL(distattn_kernel, dim3(nb * (TT / BT)), dim3(512), 0, stream,
                       x, mask, Win, bin, out);
}